// Round 1
// baseline (602.690 us; speedup 1.0000x reference)
//
#include <hip/hip_runtime.h>

static constexpr float kThresh = 0.01f;

// Monotone float <-> uint key: k(a) < k(b)  <=>  a < b  (for non-NaN floats)
__device__ __forceinline__ unsigned fkey(float f) {
    unsigned u = __float_as_uint(f);
    return (u & 0x80000000u) ? ~u : (u | 0x80000000u);
}
__device__ __forceinline__ float unkey(unsigned k) {
    unsigned u = (k & 0x80000000u) ? (k & 0x7fffffffu) : ~k;
    return __uint_as_float(u);
}

// ws layout (unsigned): [0]=smin_key [1]=smax_key [2]=lmin_key [3]=lmax_key
__global__ void kv_init_ws(unsigned* ws) {
    int t = threadIdx.x;
    if (t == 0) ws[0] = 0xFFFFFFFFu;  // min sentinel (max key)
    if (t == 1) ws[1] = 0u;           // max sentinel (min key)
    if (t == 2) ws[2] = 0xFFFFFFFFu;
    if (t == 3) ws[3] = 0u;
}

__device__ __forceinline__ void acc_one(float x, unsigned& smin, unsigned& smax,
                                        unsigned& lmin, unsigned& lmax) {
    unsigned k = fkey(x);
    if (fabsf(x) > kThresh) {
        lmin = min(lmin, k);
        lmax = max(lmax, k);
    } else {
        smin = min(smin, k);
        smax = max(smax, k);
    }
}

__global__ __launch_bounds__(256) void kv_reduce(const float* __restrict__ in, int n,
                                                 unsigned* __restrict__ ws) {
    unsigned smin = 0xFFFFFFFFu, smax = 0u, lmin = 0xFFFFFFFFu, lmax = 0u;
    const int n4 = n >> 2;
    const float4* __restrict__ in4 = (const float4*)in;
    const int stride = gridDim.x * blockDim.x;
    for (int i = blockIdx.x * blockDim.x + threadIdx.x; i < n4; i += stride) {
        float4 v = in4[i];
        acc_one(v.x, smin, smax, lmin, lmax);
        acc_one(v.y, smin, smax, lmin, lmax);
        acc_one(v.z, smin, smax, lmin, lmax);
        acc_one(v.w, smin, smax, lmin, lmax);
    }
    // scalar tail (n not divisible by 4)
    for (int i = (n4 << 2) + blockIdx.x * blockDim.x + threadIdx.x; i < n; i += stride) {
        acc_one(in[i], smin, smax, lmin, lmax);
    }
    // wave-level (64-lane) butterfly reduce
    #pragma unroll
    for (int off = 32; off > 0; off >>= 1) {
        smin = min(smin, (unsigned)__shfl_down((int)smin, off));
        smax = max(smax, (unsigned)__shfl_down((int)smax, off));
        lmin = min(lmin, (unsigned)__shfl_down((int)lmin, off));
        lmax = max(lmax, (unsigned)__shfl_down((int)lmax, off));
    }
    if ((threadIdx.x & 63) == 0) {
        atomicMin(&ws[0], smin);
        atomicMax(&ws[1], smax);
        atomicMin(&ws[2], lmin);
        atomicMax(&ws[3], lmax);
    }
}

__device__ __forceinline__ float deq1(float x, float smin, float ssc, float sis, bool sv,
                                      float lmin, float lsc, float lis, bool lv) {
    bool large = fabsf(x) > kThresh;
    float bmin = large ? lmin : smin;
    float sc   = large ? lsc : ssc;
    float is   = large ? lis : sis;
    bool  v    = large ? lv : sv;
    float q = rintf((x - bmin) * sc);         // round((x-bmin)/denom*levels), half-to-even
    float d = fmaf(q, is, bmin);              // q/levels*denom + bmin
    return v ? d : x;
}

__global__ __launch_bounds__(256) void kv_dequant(const float* __restrict__ in,
                                                  float* __restrict__ out, int n,
                                                  const unsigned* __restrict__ ws) {
    const unsigned sk0 = ws[0], sk1 = ws[1], lk0 = ws[2], lk1 = ws[3];
    // valid = has_any && (bmax != bmin)  <=>  min_key < max_key
    const bool sv = sk0 < sk1;
    const bool lv = lk0 < lk1;
    const float smin = unkey(sk0);
    const float sden = sv ? (unkey(sk1) - smin) : 1.0f;
    const float lmin = unkey(lk0);
    const float lden = lv ? (unkey(lk1) - lmin) : 1.0f;
    const float ssc = 15.0f / sden,  sis = sden / 15.0f;
    const float lsc = 255.0f / lden, lis = lden / 255.0f;

    const int n4 = n >> 2;
    const int i = blockIdx.x * blockDim.x + threadIdx.x;
    const float4* __restrict__ in4 = (const float4*)in;
    float4* __restrict__ out4 = (float4*)out;
    if (i < n4) {
        float4 v = in4[i];
        float4 r;
        r.x = deq1(v.x, smin, ssc, sis, sv, lmin, lsc, lis, lv);
        r.y = deq1(v.y, smin, ssc, sis, sv, lmin, lsc, lis, lv);
        r.z = deq1(v.z, smin, ssc, sis, sv, lmin, lsc, lis, lv);
        r.w = deq1(v.w, smin, ssc, sis, sv, lmin, lsc, lis, lv);
        out4[i] = r;
    }
    // scalar tail: first few threads of the grid cover n - n4*4 (< 4) elements
    const int tail = n - (n4 << 2);
    if (i < tail) {
        int j = (n4 << 2) + i;
        out[j] = deq1(in[j], smin, ssc, sis, sv, lmin, lsc, lis, lv);
    }
}

extern "C" void kernel_launch(void* const* d_in, const int* in_sizes, int n_in,
                              void* d_out, int out_size, void* d_ws, size_t ws_size,
                              hipStream_t stream) {
    const float* in = (const float*)d_in[0];
    float* out = (float*)d_out;
    unsigned* ws = (unsigned*)d_ws;
    const int n = in_sizes[0];

    kv_init_ws<<<1, 64, 0, stream>>>(ws);

    const int rblocks = 2048;  // grid-stride; 8 blocks/CU worth of waves
    kv_reduce<<<rblocks, 256, 0, stream>>>(in, n, ws);

    const int n4 = n >> 2;
    const int dblocks = (n4 + 255) / 256 > 0 ? (n4 + 255) / 256 : 1;
    kv_dequant<<<dblocks, 256, 0, stream>>>(in, out, n, ws);
}

// Round 2
// 243.865 us; speedup vs baseline: 2.4714x; 2.4714x over previous
//
#include <hip/hip_runtime.h>

static constexpr float kThresh = 0.01f;
static constexpr int RBLOCKS = 1024;   // stage-1 grid; 1024*4 uint partials = 16 KB staged in d_out

// Monotone float <-> uint key: k(a) < k(b)  <=>  a < b  (for non-NaN floats)
__device__ __forceinline__ unsigned fkey(float f) {
    unsigned u = __float_as_uint(f);
    return (u & 0x80000000u) ? ~u : (u | 0x80000000u);
}
__device__ __forceinline__ float unkey(unsigned k) {
    unsigned u = (k & 0x80000000u) ? (k & 0x7fffffffu) : ~k;
    return __uint_as_float(u);
}

__device__ __forceinline__ void acc_one(float x, unsigned& smin, unsigned& smax,
                                        unsigned& lmin, unsigned& lmax) {
    unsigned k = fkey(x);
    if (fabsf(x) > kThresh) {
        lmin = min(lmin, k);
        lmax = max(lmax, k);
    } else {
        smin = min(smin, k);
        smax = max(smax, k);
    }
}

__device__ __forceinline__ void wave_reduce4(unsigned& smin, unsigned& smax,
                                             unsigned& lmin, unsigned& lmax) {
    #pragma unroll
    for (int off = 32; off > 0; off >>= 1) {
        smin = min(smin, (unsigned)__shfl_down((int)smin, off));
        smax = max(smax, (unsigned)__shfl_down((int)smax, off));
        lmin = min(lmin, (unsigned)__shfl_down((int)lmin, off));
        lmax = max(lmax, (unsigned)__shfl_down((int)lmax, off));
    }
}

// Stage 1: per-block min/max partials, NO global atomics.
// partials[blockIdx*4 + {0,1,2,3}] = {smin,smax,lmin,lmax} keys.
__global__ __launch_bounds__(256) void kv_partial(const float* __restrict__ in, int n,
                                                  unsigned* __restrict__ partials) {
    unsigned smin = 0xFFFFFFFFu, smax = 0u, lmin = 0xFFFFFFFFu, lmax = 0u;
    const int n4 = n >> 2;
    const float4* __restrict__ in4 = (const float4*)in;
    const int stride = gridDim.x * blockDim.x;
    for (int i = blockIdx.x * blockDim.x + threadIdx.x; i < n4; i += stride) {
        float4 v = in4[i];
        acc_one(v.x, smin, smax, lmin, lmax);
        acc_one(v.y, smin, smax, lmin, lmax);
        acc_one(v.z, smin, smax, lmin, lmax);
        acc_one(v.w, smin, smax, lmin, lmax);
    }
    for (int i = (n4 << 2) + blockIdx.x * blockDim.x + threadIdx.x; i < n; i += stride) {
        acc_one(in[i], smin, smax, lmin, lmax);
    }

    wave_reduce4(smin, smax, lmin, lmax);

    __shared__ unsigned ls[4][4];
    const int wave = threadIdx.x >> 6;
    if ((threadIdx.x & 63) == 0) {
        ls[wave][0] = smin; ls[wave][1] = smax; ls[wave][2] = lmin; ls[wave][3] = lmax;
    }
    __syncthreads();
    if (threadIdx.x == 0) {
        unsigned a = ls[0][0], b = ls[0][1], c = ls[0][2], d = ls[0][3];
        #pragma unroll
        for (int w = 1; w < 4; ++w) {
            a = min(a, ls[w][0]); b = max(b, ls[w][1]);
            c = min(c, ls[w][2]); d = max(d, ls[w][3]);
        }
        partials[blockIdx.x * 4 + 0] = a;
        partials[blockIdx.x * 4 + 1] = b;
        partials[blockIdx.x * 4 + 2] = c;
        partials[blockIdx.x * 4 + 3] = d;
    }
}

// Stage 2: one block folds RBLOCKS partial sets into ws[0..3].
__global__ __launch_bounds__(256) void kv_final(const unsigned* __restrict__ partials,
                                                unsigned* __restrict__ ws) {
    unsigned smin = 0xFFFFFFFFu, smax = 0u, lmin = 0xFFFFFFFFu, lmax = 0u;
    for (int i = threadIdx.x; i < RBLOCKS; i += 256) {
        smin = min(smin, partials[4 * i + 0]);
        smax = max(smax, partials[4 * i + 1]);
        lmin = min(lmin, partials[4 * i + 2]);
        lmax = max(lmax, partials[4 * i + 3]);
    }
    wave_reduce4(smin, smax, lmin, lmax);

    __shared__ unsigned ls[4][4];
    const int wave = threadIdx.x >> 6;
    if ((threadIdx.x & 63) == 0) {
        ls[wave][0] = smin; ls[wave][1] = smax; ls[wave][2] = lmin; ls[wave][3] = lmax;
    }
    __syncthreads();
    if (threadIdx.x == 0) {
        unsigned a = ls[0][0], b = ls[0][1], c = ls[0][2], d = ls[0][3];
        #pragma unroll
        for (int w = 1; w < 4; ++w) {
            a = min(a, ls[w][0]); b = max(b, ls[w][1]);
            c = min(c, ls[w][2]); d = max(d, ls[w][3]);
        }
        ws[0] = a; ws[1] = b; ws[2] = c; ws[3] = d;
    }
}

__device__ __forceinline__ float deq1(float x, float smin, float ssc, float sis, bool sv,
                                      float lmin, float lsc, float lis, bool lv) {
    bool large = fabsf(x) > kThresh;
    float bmin = large ? lmin : smin;
    float sc   = large ? lsc : ssc;
    float is   = large ? lis : sis;
    bool  v    = large ? lv : sv;
    float q = rintf((x - bmin) * sc);         // round((x-bmin)/denom*levels), half-to-even
    float d = fmaf(q, is, bmin);              // q/levels*denom + bmin
    return v ? d : x;
}

__global__ __launch_bounds__(256) void kv_dequant(const float* __restrict__ in,
                                                  float* __restrict__ out, int n,
                                                  const unsigned* __restrict__ ws) {
    const unsigned sk0 = ws[0], sk1 = ws[1], lk0 = ws[2], lk1 = ws[3];
    const bool sv = sk0 < sk1;     // valid = has_any && (bmax != bmin)
    const bool lv = lk0 < lk1;
    const float smin = unkey(sk0);
    const float sden = sv ? (unkey(sk1) - smin) : 1.0f;
    const float lmin = unkey(lk0);
    const float lden = lv ? (unkey(lk1) - lmin) : 1.0f;
    const float ssc = 15.0f / sden,  sis = sden / 15.0f;
    const float lsc = 255.0f / lden, lis = lden / 255.0f;

    const int n4 = n >> 2;
    const int i = blockIdx.x * blockDim.x + threadIdx.x;
    const float4* __restrict__ in4 = (const float4*)in;
    float4* __restrict__ out4 = (float4*)out;
    if (i < n4) {
        float4 v = in4[i];
        float4 r;
        r.x = deq1(v.x, smin, ssc, sis, sv, lmin, lsc, lis, lv);
        r.y = deq1(v.y, smin, ssc, sis, sv, lmin, lsc, lis, lv);
        r.z = deq1(v.z, smin, ssc, sis, sv, lmin, lsc, lis, lv);
        r.w = deq1(v.w, smin, ssc, sis, sv, lmin, lsc, lis, lv);
        out4[i] = r;
    }
    const int tail = n - (n4 << 2);
    if (i < tail) {
        int j = (n4 << 2) + i;
        out[j] = deq1(in[j], smin, ssc, sis, sv, lmin, lsc, lis, lv);
    }
}

extern "C" void kernel_launch(void* const* d_in, const int* in_sizes, int n_in,
                              void* d_out, int out_size, void* d_ws, size_t ws_size,
                              hipStream_t stream) {
    const float* in = (const float*)d_in[0];
    float* out = (float*)d_out;
    unsigned* ws = (unsigned*)d_ws;
    const int n = in_sizes[0];

    // Stage partials in d_out (16 KB at the front) — dequant overwrites all of
    // d_out afterwards, and stream ordering serializes the three kernels.
    unsigned* partials = (unsigned*)d_out;

    kv_partial<<<RBLOCKS, 256, 0, stream>>>(in, n, partials);
    kv_final<<<1, 256, 0, stream>>>(partials, ws);

    const int n4 = n >> 2;
    int dblocks = (n4 + 255) / 256;
    if (dblocks < 1) dblocks = 1;
    kv_dequant<<<dblocks, 256, 0, stream>>>(in, out, n, ws);
}